// Round 4
// baseline (906.522 us; speedup 1.0000x reference)
//
#include <hip/hip_runtime.h>
#include <math.h>

// critic_attention, round 4: back to round-1 structure (lane = item, 64-thread
// blocks, zero barriers), with the two diagnosed fixes:
//  (a) weights fetched as VECTOR loads (divergence-poisoned pointer defeats the
//      compiler's uniform->s_load scalarization). SGPR file (~100) was capping
//      prefetch depth at <1 K-step; VGPRs at __launch_bounds__(64,1) give us
//      up to 512 regs -> deep load pipelining at 1 wave/SIMD.
//  (b) layer0 processes 2 agents per pass: each W0 quad load feeds 8 FMAs.
// Occupancy is structurally 1 wave/SIMD (65536 items = 65536 lanes chip-wide);
// all latency hiding must come from ILP, hence the fat register budget.
// WRITE_SIZE must come back to ~256 KB (rounds 2/3 spilled 94-116 MB).

#define SLOPE 0.01f
#define LOG2E 1.4426950408889634f

__device__ __forceinline__ float lrelu(float x) { return fmaxf(x, SLOPE * x); }

__device__ __forceinline__ float fast_tanh(float x) {
    float e = exp2f(x * (2.0f * LOG2E));
    return 1.0f - __fdividef(2.0f, e + 1.0f);
}

// in-place tanh of h, returns dot(tanh(h), W1o[0..63])
__device__ __forceinline__ float tanh_dot(float h[64], const float* __restrict__ W1o) {
    float d0 = 0.f, d1 = 0.f, d2 = 0.f, d3 = 0.f;
#pragma unroll
    for (int c = 0; c < 64; c += 4) {
        h[c + 0] = fast_tanh(h[c + 0]);
        h[c + 1] = fast_tanh(h[c + 1]);
        h[c + 2] = fast_tanh(h[c + 2]);
        h[c + 3] = fast_tanh(h[c + 3]);
        d0 = fmaf(h[c + 0], W1o[c + 0], d0);
        d1 = fmaf(h[c + 1], W1o[c + 1], d1);
        d2 = fmaf(h[c + 2], W1o[c + 2], d2);
        d3 = fmaf(h[c + 3], W1o[c + 3], d3);
    }
    return (d0 + d1) + (d2 + d3);
}

// online-softmax update with one agent's (already computed) h; tanh applied here
__device__ __forceinline__ void agent_update(float h[64], const float* __restrict__ W1o,
                                             float a_self, float& m, float& s,
                                             float xsum[64]) {
    float d = tanh_dot(h, W1o);
    float l = lrelu(a_self + d);
    float mn = fmaxf(m, l);
    float f = exp2f((m - mn) * LOG2E);   // m=-inf first time -> f=0
    float e = exp2f((l - mn) * LOG2E);
    s = fmaf(s, f, e);
    m = mn;
#pragma unroll
    for (int c = 0; c < 64; ++c) xsum[c] = fmaf(xsum[c], f, e * h[c]);
}

__global__ __launch_bounds__(64, 1) void critic_attention_kernel(
    const float* __restrict__ obs, const float* __restrict__ act,
    const float* __restrict__ W0, const float* __restrict__ b0,
    const float* __restrict__ W1, const float* __restrict__ b1v,
    const float* __restrict__ W2, const float* __restrict__ b2,
    const float* __restrict__ W3, const float* __restrict__ b3,
    const float* __restrict__ Wc, const float* __restrict__ bcv,
    float* __restrict__ out)
{
    __shared__ float tile[64 * 129];   // per-lane private slice, stride 129 (2-way alias = free)
    const int t = threadIdx.x;
    float* slice = tile + t * 129;

    const long item = (long)blockIdx.x * 64 + t;
    const float* orow = obs + item * 512;
    const float* arow = act + item * 128;

    // divergence poison: z is 0 at runtime but opaque to the compiler, so
    // weight addresses stay "divergent" -> global_load_dwordx4, not s_load.
    int z;
    asm volatile("v_mov_b32 %0, 0" : "=v"(z));
    const float* W0v = W0 + z;
    const float* W2v = W2 + z;
    const float* W3v = W3 + z;

    float xsum[64];
    float m = -INFINITY, s = 0.f, a_self = 0.f;
#pragma unroll
    for (int c = 0; c < 64; ++c) xsum[c] = 0.f;

    // ---------------- layer0 + attention: 8 passes x 2 agents ----------------
    for (int g = 0; g < 8; ++g) {
        float h0[64], h1[64];
#pragma unroll
        for (int cq = 0; cq < 16; ++cq) {
            float4 b = *reinterpret_cast<const float4*>(b0 + cq * 4);
            h0[cq * 4 + 0] = b.x; h1[cq * 4 + 0] = b.x;
            h0[cq * 4 + 1] = b.y; h1[cq * 4 + 1] = b.y;
            h0[cq * 4 + 2] = b.z; h1[cq * 4 + 2] = b.z;
            h0[cq * 4 + 3] = b.w; h1[cq * 4 + 3] = b.w;
        }
        const float* o0 = orow + g * 64;   // agents 2g, 2g+1: obs rows (32 each)
        const float* ap = arow + g * 16;   // act rows (8 each)

#pragma unroll 2
        for (int f4 = 0; f4 < 8; ++f4) {   // obs features 0..31
            float4 x0 = *reinterpret_cast<const float4*>(o0 + f4 * 4);
            float4 x1 = *reinterpret_cast<const float4*>(o0 + 32 + f4 * 4);
            float xs0[4] = {x0.x, x0.y, x0.z, x0.w};
            float xs1[4] = {x1.x, x1.y, x1.z, x1.w};
#pragma unroll
            for (int kf = 0; kf < 4; ++kf) {
                const float* wrow = W0v + (f4 * 4 + kf) * 64;
#pragma unroll
                for (int cq = 0; cq < 16; ++cq) {
                    float4 w = *reinterpret_cast<const float4*>(wrow + cq * 4);
                    h0[cq * 4 + 0] = fmaf(xs0[kf], w.x, h0[cq * 4 + 0]);
                    h0[cq * 4 + 1] = fmaf(xs0[kf], w.y, h0[cq * 4 + 1]);
                    h0[cq * 4 + 2] = fmaf(xs0[kf], w.z, h0[cq * 4 + 2]);
                    h0[cq * 4 + 3] = fmaf(xs0[kf], w.w, h0[cq * 4 + 3]);
                    h1[cq * 4 + 0] = fmaf(xs1[kf], w.x, h1[cq * 4 + 0]);
                    h1[cq * 4 + 1] = fmaf(xs1[kf], w.y, h1[cq * 4 + 1]);
                    h1[cq * 4 + 2] = fmaf(xs1[kf], w.z, h1[cq * 4 + 2]);
                    h1[cq * 4 + 3] = fmaf(xs1[kf], w.w, h1[cq * 4 + 3]);
                }
            }
        }
#pragma unroll
        for (int f4 = 0; f4 < 2; ++f4) {   // act features 32..39
            float4 x0 = *reinterpret_cast<const float4*>(ap + f4 * 4);
            float4 x1 = *reinterpret_cast<const float4*>(ap + 8 + f4 * 4);
            float xs0[4] = {x0.x, x0.y, x0.z, x0.w};
            float xs1[4] = {x1.x, x1.y, x1.z, x1.w};
#pragma unroll
            for (int kf = 0; kf < 4; ++kf) {
                const float* wrow = W0v + (32 + f4 * 4 + kf) * 64;
#pragma unroll
                for (int cq = 0; cq < 16; ++cq) {
                    float4 w = *reinterpret_cast<const float4*>(wrow + cq * 4);
                    h0[cq * 4 + 0] = fmaf(xs0[kf], w.x, h0[cq * 4 + 0]);
                    h0[cq * 4 + 1] = fmaf(xs0[kf], w.y, h0[cq * 4 + 1]);
                    h0[cq * 4 + 2] = fmaf(xs0[kf], w.z, h0[cq * 4 + 2]);
                    h0[cq * 4 + 3] = fmaf(xs0[kf], w.w, h0[cq * 4 + 3]);
                    h1[cq * 4 + 0] = fmaf(xs1[kf], w.x, h1[cq * 4 + 0]);
                    h1[cq * 4 + 1] = fmaf(xs1[kf], w.y, h1[cq * 4 + 1]);
                    h1[cq * 4 + 2] = fmaf(xs1[kf], w.z, h1[cq * 4 + 2]);
                    h1[cq * 4 + 3] = fmaf(xs1[kf], w.w, h1[cq * 4 + 3]);
                }
            }
        }

        if (g == 0) {
            // agent 0 (h0): x_self -> slice[0:64] + a_self
            float d0 = 0.f, d1 = 0.f, d2 = 0.f, d3 = 0.f;
#pragma unroll
            for (int c = 0; c < 64; c += 4) {
                float s0 = lrelu(h0[c + 0]);
                float s1 = lrelu(h0[c + 1]);
                float s2 = lrelu(h0[c + 2]);
                float s3 = lrelu(h0[c + 3]);
                slice[c + 0] = s0;
                slice[c + 1] = s1;
                slice[c + 2] = s2;
                slice[c + 3] = s3;
                d0 = fmaf(s0, W1[c + 0], d0);
                d1 = fmaf(s1, W1[c + 1], d1);
                d2 = fmaf(s2, W1[c + 2], d2);
                d3 = fmaf(s3, W1[c + 3], d3);
            }
            a_self = b1v[0] + ((d0 + d1) + (d2 + d3));
            agent_update(h1, W1 + 64, a_self, m, s, xsum);
        } else {
            agent_update(h0, W1 + 64, a_self, m, s, xsum);
            agent_update(h1, W1 + 64, a_self, m, s, xsum);
        }
    }

    const float inv = __fdividef(1.0f, s);
#pragma unroll
    for (int c = 0; c < 64; ++c) slice[64 + c] = xsum[c] * inv;   // x_cat[64:128]

    // ---------------- x1 = lrelu(x_cat @ W2 + b2) ----------------
    float acc[128];
#pragma unroll
    for (int j = 0; j < 128; ++j) acc[j] = b2[j];
#pragma unroll 2
    for (int i = 0; i < 128; ++i) {
        float xv = slice[i];
        const float* wr = W2v + i * 128;
#pragma unroll
        for (int jq = 0; jq < 32; ++jq) {
            float4 w = *reinterpret_cast<const float4*>(wr + jq * 4);
            acc[jq * 4 + 0] = fmaf(xv, w.x, acc[jq * 4 + 0]);
            acc[jq * 4 + 1] = fmaf(xv, w.y, acc[jq * 4 + 1]);
            acc[jq * 4 + 2] = fmaf(xv, w.z, acc[jq * 4 + 2]);
            acc[jq * 4 + 3] = fmaf(xv, w.w, acc[jq * 4 + 3]);
        }
    }
#pragma unroll
    for (int j = 0; j < 128; ++j) slice[j] = lrelu(acc[j]);   // x1 overwrites x_cat

    // ---------------- x2 = lrelu(x1 @ W3 + b3) ----------------
#pragma unroll
    for (int j = 0; j < 128; ++j) acc[j] = b3[j];
#pragma unroll 2
    for (int i = 0; i < 128; ++i) {
        float xv = slice[i];
        const float* wr = W3v + i * 128;
#pragma unroll
        for (int jq = 0; jq < 32; ++jq) {
            float4 w = *reinterpret_cast<const float4*>(wr + jq * 4);
            acc[jq * 4 + 0] = fmaf(xv, w.x, acc[jq * 4 + 0]);
            acc[jq * 4 + 1] = fmaf(xv, w.y, acc[jq * 4 + 1]);
            acc[jq * 4 + 2] = fmaf(xv, w.z, acc[jq * 4 + 2]);
            acc[jq * 4 + 3] = fmaf(xv, w.w, acc[jq * 4 + 3]);
        }
    }

    // ---------------- value = x2 @ Wc + bc ----------------
    float v0 = 0.f, v1 = 0.f, v2 = 0.f, v3 = 0.f;
#pragma unroll
    for (int j = 0; j < 128; j += 4) {
        v0 = fmaf(lrelu(acc[j + 0]), Wc[j + 0], v0);
        v1 = fmaf(lrelu(acc[j + 1]), Wc[j + 1], v1);
        v2 = fmaf(lrelu(acc[j + 2]), Wc[j + 2], v2);
        v3 = fmaf(lrelu(acc[j + 3]), Wc[j + 3], v3);
    }
    out[item] = bcv[0] + ((v0 + v1) + (v2 + v3));
}

extern "C" void kernel_launch(void* const* d_in, const int* in_sizes, int n_in,
                              void* d_out, int out_size, void* d_ws, size_t ws_size,
                              hipStream_t stream) {
    (void)in_sizes; (void)n_in; (void)d_ws; (void)ws_size; (void)out_size;
    const float* obs = (const float*)d_in[0];
    const float* act = (const float*)d_in[1];
    const float* W0  = (const float*)d_in[2];
    const float* b0  = (const float*)d_in[3];
    const float* W1  = (const float*)d_in[4];
    const float* b1  = (const float*)d_in[5];
    const float* W2  = (const float*)d_in[6];
    const float* b2  = (const float*)d_in[7];
    const float* W3  = (const float*)d_in[8];
    const float* b3  = (const float*)d_in[9];
    const float* Wc  = (const float*)d_in[10];
    const float* bc  = (const float*)d_in[11];

    critic_attention_kernel<<<dim3(65536 / 64), dim3(64), 0, stream>>>(
        obs, act, W0, b0, W1, b1, W2, b2, W3, b3, Wc, bc, (float*)d_out);
}

// Round 5
// 299.288 us; speedup vs baseline: 3.0289x; 3.0289x over previous
//
#include <hip/hip_runtime.h>
#include <math.h>

// critic_attention, round 5: agent->lane mapping for occupancy.
//
// Phase A: thread = (item, agent). 16 threads/item -> 1M threads -> 16 waves/SIMD
//   scheduled (~3-4 resident). Each lane: layer0 (40x64 fma, weights via s_load),
//   activation, attention score. Softmax over the 16-lane group via shfl_xor
//   butterflies (masks 1,2,4,8); weights are pre-normalized (w = e/sum) so the
//   weighted sum needs no online-softmax state. x_cat handed to phase B via a
//   16x129 LDS tile (odd stride -> 2-way bank alias = free).
// Phase B: wave wq + colgroup cg (lane>>4) own 8 output cols; item = lane&15.
//   W2/W3 streamed as float4 vector loads (4 distinct 32B rows per instr,
//   16-lane broadcast each), x1 written back to the tile between barriers.
// Live state: h[64]+x[40] only -> no spills (WRITE_SIZE must be ~0.5 MB).

#define SLOPE 0.01f
#define LOG2E 1.4426950408889634f

__device__ __forceinline__ float lrelu(float x) { return fmaxf(x, SLOPE * x); }

__device__ __forceinline__ float fast_tanh(float x) {
    float e = exp2f(x * (2.0f * LOG2E));
    return 1.0f - __fdividef(2.0f, e + 1.0f);
}

__global__ __launch_bounds__(256) void critic_attention_kernel(
    const float* __restrict__ obs, const float* __restrict__ act,
    const float* __restrict__ W0, const float* __restrict__ b0,
    const float* __restrict__ W1, const float* __restrict__ b1v,
    const float* __restrict__ W2, const float* __restrict__ b2,
    const float* __restrict__ W3, const float* __restrict__ b3,
    const float* __restrict__ Wc, const float* __restrict__ bcv,
    float* __restrict__ out)
{
    __shared__ float tile[16 * 129];   // x_cat then x1, block-local 16 items
    __shared__ float red[16 * 5];      // Wc cross-wave partials

    const int t = threadIdx.x;
    const int itemL = t >> 4;          // 0..15 (phase A)
    const int ag = t & 15;             // agent 0..15
    const long itemG = (long)blockIdx.x * 16 + itemL;

    // ---------------- phase A: layer0 for (item, agent) ----------------
    const float* orow = obs + itemG * 512 + ag * 32;
    const float* arow = act + itemG * 128 + ag * 8;

    float x[40];
#pragma unroll
    for (int k = 0; k < 8; ++k) {
        float4 v = *reinterpret_cast<const float4*>(orow + k * 4);
        x[k * 4 + 0] = v.x; x[k * 4 + 1] = v.y;
        x[k * 4 + 2] = v.z; x[k * 4 + 3] = v.w;
    }
#pragma unroll
    for (int k = 0; k < 2; ++k) {
        float4 v = *reinterpret_cast<const float4*>(arow + k * 4);
        x[32 + k * 4 + 0] = v.x; x[32 + k * 4 + 1] = v.y;
        x[32 + k * 4 + 2] = v.z; x[32 + k * 4 + 3] = v.w;
    }

    float h[64];
#pragma unroll
    for (int cq = 0; cq < 16; ++cq) {
        float4 b = *reinterpret_cast<const float4*>(b0 + cq * 4);
        h[cq * 4 + 0] = b.x; h[cq * 4 + 1] = b.y;
        h[cq * 4 + 2] = b.z; h[cq * 4 + 3] = b.w;
    }
#pragma unroll
    for (int f = 0; f < 40; ++f) {
        const float xf = x[f];
        const float* w = W0 + f * 64;      // uniform -> s_load
#pragma unroll
        for (int cq = 0; cq < 16; ++cq) {
            float4 wv = *reinterpret_cast<const float4*>(w + cq * 4);
            h[cq * 4 + 0] = fmaf(xf, wv.x, h[cq * 4 + 0]);
            h[cq * 4 + 1] = fmaf(xf, wv.y, h[cq * 4 + 1]);
            h[cq * 4 + 2] = fmaf(xf, wv.z, h[cq * 4 + 2]);
            h[cq * 4 + 3] = fmaf(xf, wv.w, h[cq * 4 + 3]);
        }
    }

    // activation + attention score
    float a_self = 0.f, dval = 0.f;
    if (ag == 0) {
        float d0 = 0.f, d1 = 0.f, d2 = 0.f, d3 = 0.f;
#pragma unroll
        for (int c = 0; c < 64; c += 4) {
            h[c + 0] = lrelu(h[c + 0]); h[c + 1] = lrelu(h[c + 1]);
            h[c + 2] = lrelu(h[c + 2]); h[c + 3] = lrelu(h[c + 3]);
            d0 = fmaf(h[c + 0], W1[c + 0], d0);
            d1 = fmaf(h[c + 1], W1[c + 1], d1);
            d2 = fmaf(h[c + 2], W1[c + 2], d2);
            d3 = fmaf(h[c + 3], W1[c + 3], d3);
        }
        a_self = b1v[0] + ((d0 + d1) + (d2 + d3));
#pragma unroll
        for (int c = 0; c < 64; ++c) tile[itemL * 129 + c] = h[c];  // x_self
    } else {
        float d0 = 0.f, d1 = 0.f, d2 = 0.f, d3 = 0.f;
#pragma unroll
        for (int c = 0; c < 64; c += 4) {
            h[c + 0] = fast_tanh(h[c + 0]); h[c + 1] = fast_tanh(h[c + 1]);
            h[c + 2] = fast_tanh(h[c + 2]); h[c + 3] = fast_tanh(h[c + 3]);
            d0 = fmaf(h[c + 0], W1[64 + c + 0], d0);
            d1 = fmaf(h[c + 1], W1[64 + c + 1], d1);
            d2 = fmaf(h[c + 2], W1[64 + c + 2], d2);
            d3 = fmaf(h[c + 3], W1[64 + c + 3], d3);
        }
        dval = (d0 + d1) + (d2 + d3);
    }
    a_self = __shfl(a_self, t & 48, 64);   // agent-0 lane of this item's 16-group

    // softmax over the 16-lane group (agent 0 excluded via -inf -> e = 0)
    float logit = (ag == 0) ? -INFINITY : lrelu(a_self + dval);
    float mx = logit;
#pragma unroll
    for (int mk = 1; mk <= 8; mk <<= 1)
        mx = fmaxf(mx, __shfl_xor(mx, mk, 64));
    float e = exp2f((logit - mx) * LOG2E);
    float ssum = e;
#pragma unroll
    for (int mk = 1; mk <= 8; mk <<= 1)
        ssum += __shfl_xor(ssum, mk, 64);
    const float w = __fdividef(e, ssum);   // pre-normalized attention weight

    // weighted sum across the 16-lane group: butterfly over w*h
#pragma unroll
    for (int c = 0; c < 64; ++c) h[c] *= w;
#pragma unroll
    for (int mk = 1; mk <= 8; mk <<= 1) {
#pragma unroll
        for (int c = 0; c < 64; ++c) h[c] += __shfl_xor(h[c], mk, 64);
    }
    if (ag == 0) {
#pragma unroll
        for (int c = 0; c < 64; ++c) tile[itemL * 129 + 64 + c] = h[c];  // x_sum
    }
    __syncthreads();

    // ---------------- phase B: MLP on 16 items ----------------
    const int lane = t & 63;
    const int wq = t >> 6;             // wave 0..3
    const int ib = lane & 15;          // item 0..15
    const int cg = lane >> 4;          // col subgroup 0..3
    const int jb = wq * 32 + cg * 8;   // this lane's 8 output cols

    float acc[8];
#pragma unroll
    for (int j = 0; j < 8; ++j) acc[j] = b2[jb + j];
#pragma unroll 8
    for (int i = 0; i < 128; ++i) {
        const float xv = tile[ib * 129 + i];
        const float* wr = W2 + i * 128 + jb;
        float4 wa = *reinterpret_cast<const float4*>(wr);
        float4 wb = *reinterpret_cast<const float4*>(wr + 4);
        acc[0] = fmaf(xv, wa.x, acc[0]); acc[1] = fmaf(xv, wa.y, acc[1]);
        acc[2] = fmaf(xv, wa.z, acc[2]); acc[3] = fmaf(xv, wa.w, acc[3]);
        acc[4] = fmaf(xv, wb.x, acc[4]); acc[5] = fmaf(xv, wb.y, acc[5]);
        acc[6] = fmaf(xv, wb.z, acc[6]); acc[7] = fmaf(xv, wb.w, acc[7]);
    }
    __syncthreads();   // all x_cat reads done before overwrite
#pragma unroll
    for (int j = 0; j < 8; ++j) tile[ib * 129 + jb + j] = lrelu(acc[j]);
    __syncthreads();

#pragma unroll
    for (int j = 0; j < 8; ++j) acc[j] = b3[jb + j];
#pragma unroll 8
    for (int i = 0; i < 128; ++i) {
        const float xv = tile[ib * 129 + i];
        const float* wr = W3 + i * 128 + jb;
        float4 wa = *reinterpret_cast<const float4*>(wr);
        float4 wb = *reinterpret_cast<const float4*>(wr + 4);
        acc[0] = fmaf(xv, wa.x, acc[0]); acc[1] = fmaf(xv, wa.y, acc[1]);
        acc[2] = fmaf(xv, wa.z, acc[2]); acc[3] = fmaf(xv, wa.w, acc[3]);
        acc[4] = fmaf(xv, wb.x, acc[4]); acc[5] = fmaf(xv, wb.y, acc[5]);
        acc[6] = fmaf(xv, wb.z, acc[6]); acc[7] = fmaf(xv, wb.w, acc[7]);
    }

    // value partial over this lane's 8 cols
    float v0 = 0.f, v1 = 0.f;
#pragma unroll
    for (int j = 0; j < 8; j += 2) {
        v0 = fmaf(lrelu(acc[j + 0]), Wc[jb + j + 0], v0);
        v1 = fmaf(lrelu(acc[j + 1]), Wc[jb + j + 1], v1);
    }
    float v = v0 + v1;
    v += __shfl_xor(v, 16, 64);   // sum over colgroups (same item)
    v += __shfl_xor(v, 32, 64);
    if (cg == 0) red[ib * 5 + wq] = v;
    __syncthreads();
    if (t < 16) {
        out[(long)blockIdx.x * 16 + t] =
            bcv[0] + ((red[t * 5 + 0] + red[t * 5 + 1]) +
                      (red[t * 5 + 2] + red[t * 5 + 3]));
    }
}

extern "C" void kernel_launch(void* const* d_in, const int* in_sizes, int n_in,
                              void* d_out, int out_size, void* d_ws, size_t ws_size,
                              hipStream_t stream) {
    (void)in_sizes; (void)n_in; (void)d_ws; (void)ws_size; (void)out_size;
    const float* obs = (const float*)d_in[0];
    const float* act = (const float*)d_in[1];
    const float* W0  = (const float*)d_in[2];
    const float* b0  = (const float*)d_in[3];
    const float* W1  = (const float*)d_in[4];
    const float* b1  = (const float*)d_in[5];
    const float* W2  = (const float*)d_in[6];
    const float* b2  = (const float*)d_in[7];
    const float* W3  = (const float*)d_in[8];
    const float* b3  = (const float*)d_in[9];
    const float* Wc  = (const float*)d_in[10];
    const float* bc  = (const float*)d_in[11];

    critic_attention_kernel<<<dim3(65536 / 16), dim3(256), 0, stream>>>(
        obs, act, W0, b0, W1, b1, W2, b2, W3, b3, Wc, bc, (float*)d_out);
}

// Round 6
// 177.330 us; speedup vs baseline: 5.1121x; 1.6878x over previous
//
#include <hip/hip_runtime.h>
#include <math.h>

// critic_attention, round 6: MFMA (split-fp16) for all three matmuls.
//
// Block = 64 items, 4 waves, everything wave-private (ZERO barriers).
// Phase A: per item, M-tile = its 16 agents. X[16x40] x W0[40x64] via
//   mfma_f32_16x16x32_f16, K split k0=obs(32) k1=act(8,zero-pad).
//   Split-fp16: x=xh+xl, w=wh+wl, D = Al*Bh + Ah*Bl + Ah*Bh (3 MFMA) ->
//   dropped term ~2^-22 -> fp32-grade accuracy.
//   A-frag: lane holds row (l&15), k=(l>>4)*8+e  (wave = 2KB contiguous obs).
//   D: col = l&15 (m89-verified), row = (l>>4)*4 + reg -> agent.
//   Softmax across agents = 16-lane butterflies (masks 1,2,4,8 for col-reduce,
//   16,32 for agent-group reduce). x_cat -> LDS rows (stride 132 floats:
//   16B-aligned for ds_read_b128, 2-way bank alias = free per m136).
// Phase B: per wave, M-tile = its 16 items. x_cat[16x128] x W2 -> x1 (in-place
//   LDS), x1 x W3 -> x2, dot Wc via butterfly. B-frags loaded per-lane from
//   global (L2-resident weights).

#define SLOPE 0.01f
#define LOG2E 1.4426950408889634f

typedef _Float16 f16x8 __attribute__((ext_vector_type(8)));
typedef float f32x4 __attribute__((ext_vector_type(4)));

#define MFMA(a, b, c) __builtin_amdgcn_mfma_f32_16x16x32_f16((a), (b), (c), 0, 0, 0)

__device__ __forceinline__ float lrelu(float x) { return fmaxf(x, SLOPE * x); }

__device__ __forceinline__ float fast_tanh(float x) {
    float e = exp2f(x * (2.0f * LOG2E));
    return 1.0f - __fdividef(2.0f, e + 1.0f);
}

__device__ __forceinline__ void split8(const float f[8], f16x8& hi, f16x8& lo) {
#pragma unroll
    for (int e = 0; e < 8; ++e) {
        _Float16 h = (_Float16)f[e];
        hi[e] = h;
        lo[e] = (_Float16)(f[e] - (float)h);
    }
}

__global__ __launch_bounds__(256) void critic_attention_kernel(
    const float* __restrict__ obs, const float* __restrict__ act,
    const float* __restrict__ W0, const float* __restrict__ b0,
    const float* __restrict__ W1, const float* __restrict__ b1v,
    const float* __restrict__ W2, const float* __restrict__ b2,
    const float* __restrict__ W3, const float* __restrict__ b3,
    const float* __restrict__ Wc, const float* __restrict__ bcv,
    float* __restrict__ out)
{
    __shared__ float xcat[64 * 132];   // stride 132: 16B-aligned, 2-way bank alias

    const int t = threadIdx.x;
    const int lane = t & 63;
    const int wq = t >> 6;
    const int lr = lane & 15;          // A-row / D-col index
    const int lg = lane >> 4;          // k-chunk / D-row-group

    // ---------------- preload W0 fragments (B operand: col=lr, k=(lg)*8+e) ----------------
    f16x8 w0h[2][4], w0l[2][4];
#pragma unroll
    for (int ks = 0; ks < 2; ++ks) {
#pragma unroll
        for (int ct = 0; ct < 4; ++ct) {
            float tmp[8];
#pragma unroll
            for (int e = 0; e < 8; ++e) {
                int k = ks * 32 + lg * 8 + e;
                tmp[e] = (k < 40) ? W0[k * 64 + ct * 16 + lr] : 0.f;
            }
            split8(tmp, w0h[ks][ct], w0l[ks][ct]);
        }
    }

    // per-lane column constants
    float b0c[4], W1sc[4], W1oc[4];
#pragma unroll
    for (int ct = 0; ct < 4; ++ct) {
        b0c[ct]  = b0[ct * 16 + lr];
        W1sc[ct] = W1[ct * 16 + lr];
        W1oc[ct] = W1[64 + ct * 16 + lr];
    }
    float b2c[8], b3c[8], Wcc[8];
#pragma unroll
    for (int ct = 0; ct < 8; ++ct) {
        b2c[ct] = b2[ct * 16 + lr];
        b3c[ct] = b3[ct * 16 + lr];
        Wcc[ct] = Wc[ct * 16 + lr];
    }
    const float b1s = b1v[0], bcs = bcv[0];

    const int rbase = wq * 16;
    const long ibase = (long)blockIdx.x * 64 + rbase;

    // ---------------- phase A: one item (16 agents) per M-tile ----------------
    // prefetch tile 0
    float4 q0, q1, c0, c1;
    {
        const float* op = obs + ibase * 512 + lr * 32 + lg * 8;
        q0 = *reinterpret_cast<const float4*>(op);
        q1 = *reinterpret_cast<const float4*>(op + 4);
        c0 = make_float4(0.f, 0.f, 0.f, 0.f);
        c1 = c0;
        if (lg == 0) {
            const float* ap = act + ibase * 128 + lr * 8;
            c0 = *reinterpret_cast<const float4*>(ap);
            c1 = *reinterpret_cast<const float4*>(ap + 4);
        }
    }

    for (int tt = 0; tt < 16; ++tt) {
        float a0f[8] = {q0.x, q0.y, q0.z, q0.w, q1.x, q1.y, q1.z, q1.w};
        float a1f[8] = {c0.x, c0.y, c0.z, c0.w, c1.x, c1.y, c1.z, c1.w};
        f16x8 ah0, al0, ah1, al1;
        split8(a0f, ah0, al0);
        split8(a1f, ah1, al1);

        // prefetch next tile (regs q/c dead after split)
        if (tt < 15) {
            const long In = ibase + tt + 1;
            const float* op = obs + In * 512 + lr * 32 + lg * 8;
            q0 = *reinterpret_cast<const float4*>(op);
            q1 = *reinterpret_cast<const float4*>(op + 4);
            if (lg == 0) {
                const float* ap = act + In * 128 + lr * 8;
                c0 = *reinterpret_cast<const float4*>(ap);
                c1 = *reinterpret_cast<const float4*>(ap + 4);
            }
        }

        f32x4 acc[4];
#pragma unroll
        for (int ct = 0; ct < 4; ++ct) {
            acc[ct] = (f32x4){0.f, 0.f, 0.f, 0.f};
            acc[ct] = MFMA(al0, w0h[0][ct], acc[ct]);
            acc[ct] = MFMA(ah0, w0l[0][ct], acc[ct]);
            acc[ct] = MFMA(ah0, w0h[0][ct], acc[ct]);
            acc[ct] = MFMA(al1, w0h[1][ct], acc[ct]);
            acc[ct] = MFMA(ah1, w0l[1][ct], acc[ct]);
            acc[ct] = MFMA(ah1, w0h[1][ct], acc[ct]);
        }

        // activations: lane holds agents lg*4+j, cols ct*16+lr
        float xa[4][4];
#pragma unroll
        for (int ct = 0; ct < 4; ++ct)
#pragma unroll
            for (int j = 0; j < 4; ++j)
                xa[ct][j] = fast_tanh(acc[ct][j] + b0c[ct]);
        if (lg == 0) {
#pragma unroll
            for (int ct = 0; ct < 4; ++ct)
                xa[ct][0] = lrelu(acc[ct][0] + b0c[ct]);   // agent 0 = self
        }

        // attention scores: col-partials then 16-lane butterfly
        float p[4];
#pragma unroll
        for (int j = 0; j < 4; ++j) {
            p[j] = xa[0][j] * W1oc[0];
            p[j] = fmaf(xa[1][j], W1oc[1], p[j]);
            p[j] = fmaf(xa[2][j], W1oc[2], p[j]);
            p[j] = fmaf(xa[3][j], W1oc[3], p[j]);
        }
        if (lg == 0) {   // self row uses W1[:64]
            p[0] = xa[0][0] * W1sc[0];
            p[0] = fmaf(xa[1][0], W1sc[1], p[0]);
            p[0] = fmaf(xa[2][0], W1sc[2], p[0]);
            p[0] = fmaf(xa[3][0], W1sc[3], p[0]);
        }
#pragma unroll
        for (int j = 0; j < 4; ++j) {
            p[j] += __shfl_xor(p[j], 1, 64);
            p[j] += __shfl_xor(p[j], 2, 64);
            p[j] += __shfl_xor(p[j], 4, 64);
            p[j] += __shfl_xor(p[j], 8, 64);
        }

        const float a_self = __shfl(b1s + p[0], lr, 64);   // from lg==0 lanes

        float logit[4];
#pragma unroll
        for (int j = 0; j < 4; ++j) logit[j] = lrelu(a_self + p[j]);
        if (lg == 0) logit[0] = -INFINITY;                  // exclude self

        float mx = fmaxf(fmaxf(logit[0], logit[1]), fmaxf(logit[2], logit[3]));
        mx = fmaxf(mx, __shfl_xor(mx, 16, 64));
        mx = fmaxf(mx, __shfl_xor(mx, 32, 64));
        float ev[4];
#pragma unroll
        for (int j = 0; j < 4; ++j) ev[j] = exp2f((logit[j] - mx) * LOG2E);
        float es = ((ev[0] + ev[1]) + (ev[2] + ev[3]));
        es += __shfl_xor(es, 16, 64);
        es += __shfl_xor(es, 32, 64);
        const float inv = __fdividef(1.f, es);

        float xs[4];
#pragma unroll
        for (int ct = 0; ct < 4; ++ct) {
            xs[ct] = (ev[0] * xa[ct][0] + ev[1] * xa[ct][1] +
                      ev[2] * xa[ct][2] + ev[3] * xa[ct][3]) * inv;
            xs[ct] += __shfl_xor(xs[ct], 16, 64);
            xs[ct] += __shfl_xor(xs[ct], 32, 64);
        }

        const int r = rbase + tt;
        if (lg == 0) {
#pragma unroll
            for (int ct = 0; ct < 4; ++ct)
                xcat[r * 132 + ct * 16 + lr] = xa[ct][0];          // x_self
        } else if (lg == 1) {
#pragma unroll
            for (int ct = 0; ct < 4; ++ct)
                xcat[r * 132 + 64 + ct * 16 + lr] = xs[ct];        // x_sum
        }
    }

    // ---------------- phase B: x_cat[16x128] @ W2 -> x1 -> @ W3 -> x2 -> Wc ----------------
    f32x4 acc2[8];
#pragma unroll
    for (int ct = 0; ct < 8; ++ct) acc2[ct] = (f32x4){0.f, 0.f, 0.f, 0.f};

#pragma unroll
    for (int ks = 0; ks < 4; ++ks) {
        const float* xr = xcat + (rbase + lr) * 132 + ks * 32 + lg * 8;
        float4 r0 = *reinterpret_cast<const float4*>(xr);
        float4 r1 = *reinterpret_cast<const float4*>(xr + 4);
        float av[8] = {r0.x, r0.y, r0.z, r0.w, r1.x, r1.y, r1.z, r1.w};
        f16x8 ah, al;
        split8(av, ah, al);
#pragma unroll
        for (int ct = 0; ct < 8; ++ct) {
            float bv[8];
#pragma unroll
            for (int e = 0; e < 8; ++e)
                bv[e] = W2[(ks * 32 + lg * 8 + e) * 128 + ct * 16 + lr];
            f16x8 bh, bl;
            split8(bv, bh, bl);
            acc2[ct] = MFMA(al, bh, acc2[ct]);
            acc2[ct] = MFMA(ah, bl, acc2[ct]);
            acc2[ct] = MFMA(ah, bh, acc2[ct]);
        }
    }
    // x1 -> LDS (in place; same wave's rows only)
#pragma unroll
    for (int ct = 0; ct < 8; ++ct)
#pragma unroll
        for (int j = 0; j < 4; ++j)
            xcat[(rbase + lg * 4 + j) * 132 + ct * 16 + lr] =
                lrelu(acc2[ct][j] + b2c[ct]);

#pragma unroll
    for (int ct = 0; ct < 8; ++ct) acc2[ct] = (f32x4){0.f, 0.f, 0.f, 0.f};
#pragma unroll
    for (int ks = 0; ks < 4; ++ks) {
        const float* xr = xcat + (rbase + lr) * 132 + ks * 32 + lg * 8;
        float4 r0 = *reinterpret_cast<const float4*>(xr);
        float4 r1 = *reinterpret_cast<const float4*>(xr + 4);
        float av[8] = {r0.x, r0.y, r0.z, r0.w, r1.x, r1.y, r1.z, r1.w};
        f16x8 ah, al;
        split8(av, ah, al);
#pragma unroll
        for (int ct = 0; ct < 8; ++ct) {
            float bv[8];
#pragma unroll
            for (int e = 0; e < 8; ++e)
                bv[e] = W3[(ks * 32 + lg * 8 + e) * 128 + ct * 16 + lr];
            f16x8 bh, bl;
            split8(bv, bh, bl);
            acc2[ct] = MFMA(al, bh, acc2[ct]);
            acc2[ct] = MFMA(ah, bl, acc2[ct]);
            acc2[ct] = MFMA(ah, bh, acc2[ct]);
        }
    }

    // value: per-lane col partials, butterfly over the 16 cols
    float v[4];
#pragma unroll
    for (int j = 0; j < 4; ++j) {
        v[j] = lrelu(acc2[0][j] + b3c[0]) * Wcc[0];
#pragma unroll
        for (int ct = 1; ct < 8; ++ct)
            v[j] = fmaf(lrelu(acc2[ct][j] + b3c[ct]), Wcc[ct], v[j]);
        v[j] += __shfl_xor(v[j], 1, 64);
        v[j] += __shfl_xor(v[j], 2, 64);
        v[j] += __shfl_xor(v[j], 4, 64);
        v[j] += __shfl_xor(v[j], 8, 64);
    }
    if (lr == 0) {
#pragma unroll
        for (int j = 0; j < 4; ++j)
            out[ibase + lg * 4 + j] = v[j] + bcs;
    }
}

extern "C" void kernel_launch(void* const* d_in, const int* in_sizes, int n_in,
                              void* d_out, int out_size, void* d_ws, size_t ws_size,
                              hipStream_t stream) {
    (void)in_sizes; (void)n_in; (void)d_ws; (void)ws_size; (void)out_size;
    const float* obs = (const float*)d_in[0];
    const float* act = (const float*)d_in[1];
    const float* W0  = (const float*)d_in[2];
    const float* b0  = (const float*)d_in[3];
    const float* W1  = (const float*)d_in[4];
    const float* b1  = (const float*)d_in[5];
    const float* W2  = (const float*)d_in[6];
    const float* b2  = (const float*)d_in[7];
    const float* W3  = (const float*)d_in[8];
    const float* b3  = (const float*)d_in[9];
    const float* Wc  = (const float*)d_in[10];
    const float* bc  = (const float*)d_in[11];

    critic_attention_kernel<<<dim3(65536 / 64), dim3(256), 0, stream>>>(
        obs, act, W0, b0, W1, b1, W2, b2, W3, b3, Wc, bc, (float*)d_out);
}

// Round 7
// 110.401 us; speedup vs baseline: 8.2112x; 1.6062x over previous
//
#include <hip/hip_runtime.h>
#include <math.h>

// critic_attention, round 7: transposed phase A (M = 16 items, online softmax
// over the agent loop in registers - flash-attention style, no softmax
// shuffles) + weights pre-split to fp16 hi/lo fragments in d_ws by a prep
// kernel (phase B: 64 coalesced 16B loads instead of 512 scalar gathers).
//
// Fragment conventions (m89-verified, validated by round 6's pass):
//   A-frag: lane holds row (l&15), k = (l>>4)*8 + e
//   B-frag: lane holds col (l&15), k = (l>>4)*8 + e
//   D:      lane holds col (l&15), row = (l>>4)*4 + reg
// Split-fp16: x = xh + xl, w = wh + wl; D = Al*Bh + Ah*Bl + Ah*Bh (3 MFMA).
//
// ws layout (halfs): W0h@0[2][4][4][16][8] W0l@4096 | W2h@8192[4][8][4][16][8]
//   W2l@24576 | W3h@40960 W3l@57344.  Total 73728 halfs = 147456 B.

#define SLOPE 0.01f
#define LOG2E 1.4426950408889634f

typedef _Float16 f16x8 __attribute__((ext_vector_type(8)));
typedef float f32x4 __attribute__((ext_vector_type(4)));

#define MFMA(a, b, c) __builtin_amdgcn_mfma_f32_16x16x32_f16((a), (b), (c), 0, 0, 0)

__device__ __forceinline__ float lrelu(float x) { return fmaxf(x, SLOPE * x); }

__device__ __forceinline__ float fast_tanh(float x) {
    float e = exp2f(x * (2.0f * LOG2E));
    return 1.0f - __fdividef(2.0f, e + 1.0f);
}

__device__ __forceinline__ void split8(const float f[8], f16x8& hi, f16x8& lo) {
#pragma unroll
    for (int e = 0; e < 8; ++e) {
        _Float16 h = (_Float16)f[e];
        hi[e] = h;
        lo[e] = (_Float16)(f[e] - (float)h);
    }
}

// ---------------- prep: split weights into per-lane fp16 hi/lo fragments ----------------
__global__ __launch_bounds__(256) void pack_weights(
    const float* __restrict__ W0, const float* __restrict__ W2,
    const float* __restrict__ W3, _Float16* __restrict__ ws)
{
    const int g = blockIdx.x * 256 + threadIdx.x;   // fragment group id
    if (g >= 4608) return;

    const float* src;
    int ks, ct, lg, lr, ncol, kmax;
    long hoff, loff;
    if (g < 512) {                       // W0: [2][4][4][16]
        ks = g >> 8; ct = (g >> 6) & 3; lg = (g >> 4) & 3; lr = g & 15;
        src = W0; ncol = 64; kmax = 40;
        hoff = (long)g * 8;  loff = hoff + 4096;
    } else if (g < 2560) {               // W2: [4][8][4][16]
        int gg = g - 512;
        ks = gg >> 9; ct = (gg >> 6) & 7; lg = (gg >> 4) & 3; lr = gg & 15;
        src = W2; ncol = 128; kmax = 128;
        hoff = 8192 + (long)gg * 8; loff = hoff + 16384;
    } else {                             // W3: [4][8][4][16]
        int gg = g - 2560;
        ks = gg >> 9; ct = (gg >> 6) & 7; lg = (gg >> 4) & 3; lr = gg & 15;
        src = W3; ncol = 128; kmax = 128;
        hoff = 40960 + (long)gg * 8; loff = hoff + 16384;
    }

    f16x8 hi, lo;
#pragma unroll
    for (int e = 0; e < 8; ++e) {
        const int k = ks * 32 + lg * 8 + e;
        const float v = (k < kmax) ? src[(long)k * ncol + ct * 16 + lr] : 0.f;
        _Float16 h = (_Float16)v;
        hi[e] = h;
        lo[e] = (_Float16)(v - (float)h);
    }
    *reinterpret_cast<f16x8*>(ws + hoff) = hi;
    *reinterpret_cast<f16x8*>(ws + loff) = lo;
}

__global__ __launch_bounds__(256) void critic_attention_kernel(
    const float* __restrict__ obs, const float* __restrict__ act,
    const float* __restrict__ b0, const float* __restrict__ W1,
    const float* __restrict__ b1v, const float* __restrict__ b2,
    const float* __restrict__ b3, const float* __restrict__ Wc,
    const float* __restrict__ bcv, const _Float16* __restrict__ ws,
    float* __restrict__ out)
{
    __shared__ float xcat[64 * 132];   // stride 132: 16B-aligned, 2-way bank alias

    const int t = threadIdx.x;
    const int lane = t & 63;
    const int wq = t >> 6;
    const int lr = lane & 15;          // item row (phase A) / A-row & D-col
    const int lg = lane >> 4;          // k-chunk / D-row-group

    const int rbase = wq * 16;
    const long ibase = (long)blockIdx.x * 64 + rbase;

    // W0 fragments from ws (stay in regs through the agent loop)
    f16x8 w0h[2][4], w0l[2][4];
#pragma unroll
    for (int ks = 0; ks < 2; ++ks)
#pragma unroll
        for (int ct = 0; ct < 4; ++ct) {
            const long o = (((long)(ks * 4 + ct) * 4 + lg) * 16 + lr) * 8;
            w0h[ks][ct] = *reinterpret_cast<const f16x8*>(ws + o);
            w0l[ks][ct] = *reinterpret_cast<const f16x8*>(ws + 4096 + o);
        }

    float b0c[4], W1sc[4], W1oc[4];
#pragma unroll
    for (int ct = 0; ct < 4; ++ct) {
        b0c[ct]  = b0[ct * 16 + lr];
        W1sc[ct] = W1[ct * 16 + lr];
        W1oc[ct] = W1[64 + ct * 16 + lr];
    }
    const float b1s = b1v[0];

    // ---------------- phase A: items = rows, loop agents, online softmax ----------------
    const float* obase = obs + (ibase + lr) * 512 + lg * 8;   // this lane's item row
    const float* abase = act + (ibase + lr) * 128;            // lg==0 lanes only

    float4 q0 = *reinterpret_cast<const float4*>(obase);
    float4 q1 = *reinterpret_cast<const float4*>(obase + 4);
    float4 c0 = make_float4(0.f, 0.f, 0.f, 0.f), c1 = c0;
    if (lg == 0) {
        c0 = *reinterpret_cast<const float4*>(abase);
        c1 = *reinterpret_cast<const float4*>(abase + 4);
    }

    float a_self[4], m[4], s[4], xsum[4][4];
#pragma unroll
    for (int j = 0; j < 4; ++j) {
        m[j] = -INFINITY; s[j] = 0.f;
#pragma unroll
        for (int ct = 0; ct < 4; ++ct) xsum[ct][j] = 0.f;
    }

    for (int a = 0; a < 16; ++a) {
        float a0f[8] = {q0.x, q0.y, q0.z, q0.w, q1.x, q1.y, q1.z, q1.w};
        float a1f[8] = {c0.x, c0.y, c0.z, c0.w, c1.x, c1.y, c1.z, c1.w};
        f16x8 ah0, al0, ah1, al1;
        split8(a0f, ah0, al0);
        split8(a1f, ah1, al1);

        if (a < 15) {   // prefetch next agent
            q0 = *reinterpret_cast<const float4*>(obase + (a + 1) * 32);
            q1 = *reinterpret_cast<const float4*>(obase + (a + 1) * 32 + 4);
            if (lg == 0) {
                c0 = *reinterpret_cast<const float4*>(abase + (a + 1) * 8);
                c1 = *reinterpret_cast<const float4*>(abase + (a + 1) * 8 + 4);
            }
        }

        f32x4 acc[4];
#pragma unroll
        for (int ct = 0; ct < 4; ++ct) {
            acc[ct] = (f32x4){0.f, 0.f, 0.f, 0.f};
            acc[ct] = MFMA(al0, w0h[0][ct], acc[ct]);
            acc[ct] = MFMA(ah0, w0l[0][ct], acc[ct]);
            acc[ct] = MFMA(ah0, w0h[0][ct], acc[ct]);
            acc[ct] = MFMA(al1, w0h[1][ct], acc[ct]);
            acc[ct] = MFMA(ah1, w0l[1][ct], acc[ct]);
            acc[ct] = MFMA(ah1, w0h[1][ct], acc[ct]);
        }

        if (a == 0) {
            // self: lrelu, a_self, x_self -> LDS
            float xa[4][4];
            float p[4];
#pragma unroll
            for (int j = 0; j < 4; ++j) {
#pragma unroll
                for (int ct = 0; ct < 4; ++ct)
                    xa[ct][j] = lrelu(acc[ct][j] + b0c[ct]);
                p[j] = xa[0][j] * W1sc[0];
                p[j] = fmaf(xa[1][j], W1sc[1], p[j]);
                p[j] = fmaf(xa[2][j], W1sc[2], p[j]);
                p[j] = fmaf(xa[3][j], W1sc[3], p[j]);
                p[j] += __shfl_xor(p[j], 1, 64);
                p[j] += __shfl_xor(p[j], 2, 64);
                p[j] += __shfl_xor(p[j], 4, 64);
                p[j] += __shfl_xor(p[j], 8, 64);
                a_self[j] = b1s + p[j];
            }
#pragma unroll
            for (int ct = 0; ct < 4; ++ct)
#pragma unroll
                for (int j = 0; j < 4; ++j)
                    xcat[(rbase + lg * 4 + j) * 132 + ct * 16 + lr] = xa[ct][j];
        } else {
            float xa[4][4];
            float p[4];
#pragma unroll
            for (int j = 0; j < 4; ++j) {
#pragma unroll
                for (int ct = 0; ct < 4; ++ct)
                    xa[ct][j] = fast_tanh(acc[ct][j] + b0c[ct]);
                p[j] = xa[0][j] * W1oc[0];
                p[j] = fmaf(xa[1][j], W1oc[1], p[j]);
                p[j] = fmaf(xa[2][j], W1oc[2], p[j]);
                p[j] = fmaf(xa[3][j], W1oc[3], p[j]);
                p[j] += __shfl_xor(p[j], 1, 64);
                p[j] += __shfl_xor(p[j], 2, 64);
                p[j] += __shfl_xor(p[j], 4, 64);
                p[j] += __shfl_xor(p[j], 8, 64);
            }
            // online softmax update, all in registers
#pragma unroll
            for (int j = 0; j < 4; ++j) {
                const float logit = lrelu(a_self[j] + p[j]);
                const float mn = fmaxf(m[j], logit);
                const float f = exp2f((m[j] - mn) * LOG2E);   // a==1: exp2(-inf)=0
                const float e = exp2f((logit - mn) * LOG2E);
                s[j] = fmaf(s[j], f, e);
                m[j] = mn;
#pragma unroll
                for (int ct = 0; ct < 4; ++ct)
                    xsum[ct][j] = fmaf(xsum[ct][j], f, e * xa[ct][j]);
            }
        }
    }

    // x_sum -> LDS
#pragma unroll
    for (int j = 0; j < 4; ++j) {
        const float inv = __fdividef(1.f, s[j]);
#pragma unroll
        for (int ct = 0; ct < 4; ++ct)
            xcat[(rbase + lg * 4 + j) * 132 + 64 + ct * 16 + lr] = xsum[ct][j] * inv;
    }

    // ---------------- phase B: x_cat[16x128] @ W2 -> x1 -> @ W3 -> x2 -> Wc ----------------
    float b2c[8], b3c[8], Wcc[8];
#pragma unroll
    for (int ct = 0; ct < 8; ++ct) {
        b2c[ct] = b2[ct * 16 + lr];
        b3c[ct] = b3[ct * 16 + lr];
        Wcc[ct] = Wc[ct * 16 + lr];
    }
    const float bcs = bcv[0];

    f32x4 acc2[8];
#pragma unroll
    for (int ct = 0; ct < 8; ++ct) acc2[ct] = (f32x4){0.f, 0.f, 0.f, 0.f};
#pragma unroll
    for (int ks = 0; ks < 4; ++ks) {
        const float* xr = xcat + (rbase + lr) * 132 + ks * 32 + lg * 8;
        float4 r0 = *reinterpret_cast<const float4*>(xr);
        float4 r1 = *reinterpret_cast<const float4*>(xr + 4);
        float av[8] = {r0.x, r0.y, r0.z, r0.w, r1.x, r1.y, r1.z, r1.w};
        f16x8 ah, al;
        split8(av, ah, al);
#pragma unroll
        for (int ct = 0; ct < 8; ++ct) {
            const long gg = ((long)(ks * 8 + ct) * 4 + lg) * 16 + lr;
            f16x8 bh = *reinterpret_cast<const f16x8*>(ws + 8192 + gg * 8);
            f16x8 bl = *reinterpret_cast<const f16x8*>(ws + 24576 + gg * 8);
            acc2[ct] = MFMA(al, bh, acc2[ct]);
            acc2[ct] = MFMA(ah, bl, acc2[ct]);
            acc2[ct] = MFMA(ah, bh, acc2[ct]);
        }
    }
#pragma unroll
    for (int ct = 0; ct < 8; ++ct)
#pragma unroll
        for (int j = 0; j < 4; ++j)
            xcat[(rbase + lg * 4 + j) * 132 + ct * 16 + lr] =
                lrelu(acc2[ct][j] + b2c[ct]);

#pragma unroll
    for (int ct = 0; ct < 8; ++ct) acc2[ct] = (f32x4){0.f, 0.f, 0.f, 0.f};
#pragma unroll
    for (int ks = 0; ks < 4; ++ks) {
        const float* xr = xcat + (rbase + lr) * 132 + ks * 32 + lg * 8;
        float4 r0 = *reinterpret_cast<const float4*>(xr);
        float4 r1 = *reinterpret_cast<const float4*>(xr + 4);
        float av[8] = {r0.x, r0.y, r0.z, r0.w, r1.x, r1.y, r1.z, r1.w};
        f16x8 ah, al;
        split8(av, ah, al);
#pragma unroll
        for (int ct = 0; ct < 8; ++ct) {
            const long gg = ((long)(ks * 8 + ct) * 4 + lg) * 16 + lr;
            f16x8 bh = *reinterpret_cast<const f16x8*>(ws + 40960 + gg * 8);
            f16x8 bl = *reinterpret_cast<const f16x8*>(ws + 57344 + gg * 8);
            acc2[ct] = MFMA(al, bh, acc2[ct]);
            acc2[ct] = MFMA(ah, bl, acc2[ct]);
            acc2[ct] = MFMA(ah, bh, acc2[ct]);
        }
    }

    // value: per-lane col partials, butterfly over the 16 cols
    float v[4];
#pragma unroll
    for (int j = 0; j < 4; ++j) {
        v[j] = lrelu(acc2[0][j] + b3c[0]) * Wcc[0];
#pragma unroll
        for (int ct = 1; ct < 8; ++ct)
            v[j] = fmaf(lrelu(acc2[ct][j] + b3c[ct]), Wcc[ct], v[j]);
        v[j] += __shfl_xor(v[j], 1, 64);
        v[j] += __shfl_xor(v[j], 2, 64);
        v[j] += __shfl_xor(v[j], 4, 64);
        v[j] += __shfl_xor(v[j], 8, 64);
    }
    if (lr == 0) {
#pragma unroll
        for (int j = 0; j < 4; ++j)
            out[ibase + lg * 4 + j] = v[j] + bcs;
    }
}

extern "C" void kernel_launch(void* const* d_in, const int* in_sizes, int n_in,
                              void* d_out, int out_size, void* d_ws, size_t ws_size,
                              hipStream_t stream) {
    (void)in_sizes; (void)n_in; (void)ws_size; (void)out_size;
    const float* obs = (const float*)d_in[0];
    const float* act = (const float*)d_in[1];
    const float* W0  = (const float*)d_in[2];
    const float* b0  = (const float*)d_in[3];
    const float* W1  = (const float*)d_in[4];
    const float* b1  = (const float*)d_in[5];
    const float* W2  = (const float*)d_in[6];
    const float* b2  = (const float*)d_in[7];
    const float* W3  = (const float*)d_in[8];
    const float* b3  = (const float*)d_in[9];
    const float* Wc  = (const float*)d_in[10];
    const float* bc  = (const float*)d_in[11];
    _Float16* ws = (_Float16*)d_ws;

    pack_weights<<<dim3(18), dim3(256), 0, stream>>>(W0, W2, W3, ws);
    critic_attention_kernel<<<dim3(65536 / 64), dim3(256), 0, stream>>>(
        obs, act, b0, W1, b1, b2, b3, Wc, bc, ws, (float*)d_out);
}

// Round 8
// 93.732 us; speedup vs baseline: 9.6714x; 1.1778x over previous
//
#include <hip/hip_runtime.h>
#include <math.h>

// critic_attention, round 8: round-7 MFMA structure with
//  (1) 1-wave blocks (64 thr, grid 4096): wave-private kernel -> no barriers
//      needed; LDS/block drops 33.8KB -> 8.4KB so up to ~18 blocks/CU resident
//      (vs 4), fixing the 20% occupancy.
//  (2) softmax without max-subtraction: logits bounded (~|a_self|+|d| <= ~6,
//      e^logit < 1e3, fp32-safe) -> s = sum e, xsum = sum e*xa. Kills the
//      serial per-agent rescale chain and ~35 VALU/agent.
//  (3) self agent peeled before the 15-agent loop.
//
// Fragment conventions (m89-verified, validated rounds 6/7):
//   A-frag: lane holds row (l&15), k = (l>>4)*8 + e
//   B-frag: lane holds col (l&15), k = (l>>4)*8 + e
//   D:      lane holds col (l&15), row = (l>>4)*4 + reg
// Split-fp16: x = xh + xl, w = wh + wl; D = Al*Bh + Ah*Bl + Ah*Bh (3 MFMA).
//
// ws layout (halfs): W0h@0[2][4][4][16][8] W0l@4096 | W2h@8192[4][8][4][16][8]
//   W2l@24576 | W3h@40960 W3l@57344.  Total 73728 halfs = 147456 B.

#define SLOPE 0.01f
#define LOG2E 1.4426950408889634f

typedef _Float16 f16x8 __attribute__((ext_vector_type(8)));
typedef float f32x4 __attribute__((ext_vector_type(4)));

#define MFMA(a, b, c) __builtin_amdgcn_mfma_f32_16x16x32_f16((a), (b), (c), 0, 0, 0)

__device__ __forceinline__ float lrelu(float x) { return fmaxf(x, SLOPE * x); }

__device__ __forceinline__ float fast_tanh(float x) {
    float e = exp2f(x * (2.0f * LOG2E));
    return 1.0f - __fdividef(2.0f, e + 1.0f);
}

__device__ __forceinline__ void split8(const float f[8], f16x8& hi, f16x8& lo) {
#pragma unroll
    for (int e = 0; e < 8; ++e) {
        _Float16 h = (_Float16)f[e];
        hi[e] = h;
        lo[e] = (_Float16)(f[e] - (float)h);
    }
}

// ---------------- prep: split weights into per-lane fp16 hi/lo fragments ----------------
__global__ __launch_bounds__(256) void pack_weights(
    const float* __restrict__ W0, const float* __restrict__ W2,
    const float* __restrict__ W3, _Float16* __restrict__ ws)
{
    const int g = blockIdx.x * 256 + threadIdx.x;   // fragment group id
    if (g >= 4608) return;

    const float* src;
    int ks, ct, lg, lr, ncol, kmax;
    long hoff, loff;
    if (g < 512) {                       // W0: [2][4][4][16]
        ks = g >> 8; ct = (g >> 6) & 3; lg = (g >> 4) & 3; lr = g & 15;
        src = W0; ncol = 64; kmax = 40;
        hoff = (long)g * 8;  loff = hoff + 4096;
    } else if (g < 2560) {               // W2: [4][8][4][16]
        int gg = g - 512;
        ks = gg >> 9; ct = (gg >> 6) & 7; lg = (gg >> 4) & 3; lr = gg & 15;
        src = W2; ncol = 128; kmax = 128;
        hoff = 8192 + (long)gg * 8; loff = hoff + 16384;
    } else {                             // W3: [4][8][4][16]
        int gg = g - 2560;
        ks = gg >> 9; ct = (gg >> 6) & 7; lg = (gg >> 4) & 3; lr = gg & 15;
        src = W3; ncol = 128; kmax = 128;
        hoff = 40960 + (long)gg * 8; loff = hoff + 16384;
    }

    f16x8 hi, lo;
#pragma unroll
    for (int e = 0; e < 8; ++e) {
        const int k = ks * 32 + lg * 8 + e;
        const float v = (k < kmax) ? src[(long)k * ncol + ct * 16 + lr] : 0.f;
        _Float16 h = (_Float16)v;
        hi[e] = h;
        lo[e] = (_Float16)(v - (float)h);
    }
    *reinterpret_cast<f16x8*>(ws + hoff) = hi;
    *reinterpret_cast<f16x8*>(ws + loff) = lo;
}

__global__ __launch_bounds__(64) void critic_attention_kernel(
    const float* __restrict__ obs, const float* __restrict__ act,
    const float* __restrict__ b0, const float* __restrict__ W1,
    const float* __restrict__ b1v, const float* __restrict__ b2,
    const float* __restrict__ b3, const float* __restrict__ Wc,
    const float* __restrict__ bcv, const _Float16* __restrict__ ws,
    float* __restrict__ out)
{
    __shared__ float xcat[16 * 132];   // one wave's 16 items; stride 132 = 16B-aligned

    const int lane = threadIdx.x;      // 0..63
    const int lr = lane & 15;          // item row (A) / D-col
    const int lg = lane >> 4;          // k-chunk / D-row-group

    const long ibase = (long)blockIdx.x * 16;

    // W0 fragments from ws (stay in regs through the agent loop)
    f16x8 w0h[2][4], w0l[2][4];
#pragma unroll
    for (int ks = 0; ks < 2; ++ks)
#pragma unroll
        for (int ct = 0; ct < 4; ++ct) {
            const long o = (((long)(ks * 4 + ct) * 4 + lg) * 16 + lr) * 8;
            w0h[ks][ct] = *reinterpret_cast<const f16x8*>(ws + o);
            w0l[ks][ct] = *reinterpret_cast<const f16x8*>(ws + 4096 + o);
        }

    float b0c[4], W1sc[4], W1oc[4];
#pragma unroll
    for (int ct = 0; ct < 4; ++ct) {
        b0c[ct]  = b0[ct * 16 + lr];
        W1sc[ct] = W1[ct * 16 + lr];
        W1oc[ct] = W1[64 + ct * 16 + lr];
    }
    const float b1s = b1v[0];

    const float* obase = obs + (ibase + lr) * 512 + lg * 8;   // this lane's item row
    const float* abase = act + (ibase + lr) * 128;            // lg==0 lanes only

    float4 q0 = *reinterpret_cast<const float4*>(obase);
    float4 q1 = *reinterpret_cast<const float4*>(obase + 4);
    float4 c0 = make_float4(0.f, 0.f, 0.f, 0.f), c1 = c0;
    if (lg == 0) {
        c0 = *reinterpret_cast<const float4*>(abase);
        c1 = *reinterpret_cast<const float4*>(abase + 4);
    }

    // ---------------- agent 0 (self) ----------------
    float a_self[4], s[4], xsum[4][4];
    {
        float a0f[8] = {q0.x, q0.y, q0.z, q0.w, q1.x, q1.y, q1.z, q1.w};
        float a1f[8] = {c0.x, c0.y, c0.z, c0.w, c1.x, c1.y, c1.z, c1.w};
        f16x8 ah0, al0, ah1, al1;
        split8(a0f, ah0, al0);
        split8(a1f, ah1, al1);

        // prefetch agent 1
        q0 = *reinterpret_cast<const float4*>(obase + 32);
        q1 = *reinterpret_cast<const float4*>(obase + 36);
        if (lg == 0) {
            c0 = *reinterpret_cast<const float4*>(abase + 8);
            c1 = *reinterpret_cast<const float4*>(abase + 12);
        }

        f32x4 acc[4];
#pragma unroll
        for (int ct = 0; ct < 4; ++ct) {
            acc[ct] = (f32x4){0.f, 0.f, 0.f, 0.f};
            acc[ct] = MFMA(al0, w0h[0][ct], acc[ct]);
            acc[ct] = MFMA(ah0, w0l[0][ct], acc[ct]);
            acc[ct] = MFMA(ah0, w0h[0][ct], acc[ct]);
            acc[ct] = MFMA(al1, w0h[1][ct], acc[ct]);
            acc[ct] = MFMA(ah1, w0l[1][ct], acc[ct]);
            acc[ct] = MFMA(ah1, w0h[1][ct], acc[ct]);
        }

        float xa[4][4], p[4];
#pragma unroll
        for (int j = 0; j < 4; ++j) {
#pragma unroll
            for (int ct = 0; ct < 4; ++ct)
                xa[ct][j] = lrelu(acc[ct][j] + b0c[ct]);
            p[j] = xa[0][j] * W1sc[0];
            p[j] = fmaf(xa[1][j], W1sc[1], p[j]);
            p[j] = fmaf(xa[2][j], W1sc[2], p[j]);
            p[j] = fmaf(xa[3][j], W1sc[3], p[j]);
            p[j] += __shfl_xor(p[j], 1, 64);
            p[j] += __shfl_xor(p[j], 2, 64);
            p[j] += __shfl_xor(p[j], 4, 64);
            p[j] += __shfl_xor(p[j], 8, 64);
            a_self[j] = b1s + p[j];
            s[j] = 0.f;
#pragma unroll
            for (int ct = 0; ct < 4; ++ct) xsum[ct][j] = 0.f;
        }
#pragma unroll
        for (int ct = 0; ct < 4; ++ct)
#pragma unroll
            for (int j = 0; j < 4; ++j)
                xcat[(lg * 4 + j) * 132 + ct * 16 + lr] = xa[ct][j];   // x_self
    }

    // ---------------- agents 1..15: no-max online softmax ----------------
    for (int a = 1; a < 16; ++a) {
        float a0f[8] = {q0.x, q0.y, q0.z, q0.w, q1.x, q1.y, q1.z, q1.w};
        float a1f[8] = {c0.x, c0.y, c0.z, c0.w, c1.x, c1.y, c1.z, c1.w};
        f16x8 ah0, al0, ah1, al1;
        split8(a0f, ah0, al0);
        split8(a1f, ah1, al1);

        if (a < 15) {   // prefetch next agent
            q0 = *reinterpret_cast<const float4*>(obase + (a + 1) * 32);
            q1 = *reinterpret_cast<const float4*>(obase + (a + 1) * 32 + 4);
            if (lg == 0) {
                c0 = *reinterpret_cast<const float4*>(abase + (a + 1) * 8);
                c1 = *reinterpret_cast<const float4*>(abase + (a + 1) * 8 + 4);
            }
        }

        f32x4 acc[4];
#pragma unroll
        for (int ct = 0; ct < 4; ++ct) {
            acc[ct] = (f32x4){0.f, 0.f, 0.f, 0.f};
            acc[ct] = MFMA(al0, w0h[0][ct], acc[ct]);
            acc[ct] = MFMA(ah0, w0l[0][ct], acc[ct]);
            acc[ct] = MFMA(ah0, w0h[0][ct], acc[ct]);
            acc[ct] = MFMA(al1, w0h[1][ct], acc[ct]);
            acc[ct] = MFMA(ah1, w0l[1][ct], acc[ct]);
            acc[ct] = MFMA(ah1, w0h[1][ct], acc[ct]);
        }

        float xa[4][4], p[4];
#pragma unroll
        for (int j = 0; j < 4; ++j) {
#pragma unroll
            for (int ct = 0; ct < 4; ++ct)
                xa[ct][j] = fast_tanh(acc[ct][j] + b0c[ct]);
            p[j] = xa[0][j] * W1oc[0];
            p[j] = fmaf(xa[1][j], W1oc[1], p[j]);
            p[j] = fmaf(xa[2][j], W1oc[2], p[j]);
            p[j] = fmaf(xa[3][j], W1oc[3], p[j]);
            p[j] += __shfl_xor(p[j], 1, 64);
            p[j] += __shfl_xor(p[j], 2, 64);
            p[j] += __shfl_xor(p[j], 4, 64);
            p[j] += __shfl_xor(p[j], 8, 64);
        }
        // logits bounded (<= ~6): softmax without max-subtraction, pure accumulation
#pragma unroll
        for (int j = 0; j < 4; ++j) {
            const float e = exp2f(lrelu(a_self[j] + p[j]) * LOG2E);
            s[j] += e;
#pragma unroll
            for (int ct = 0; ct < 4; ++ct)
                xsum[ct][j] = fmaf(e, xa[ct][j], xsum[ct][j]);
        }
    }

    // x_sum -> LDS
#pragma unroll
    for (int j = 0; j < 4; ++j) {
        const float inv = __fdividef(1.f, s[j]);
#pragma unroll
        for (int ct = 0; ct < 4; ++ct)
            xcat[(lg * 4 + j) * 132 + 64 + ct * 16 + lr] = xsum[ct][j] * inv;
    }

    // ---------------- phase B: x_cat[16x128] @ W2 -> x1 -> @ W3 -> x2 -> Wc ----------------
    float b2c[8], b3c[8], Wcc[8];
#pragma unroll
    for (int ct = 0; ct < 8; ++ct) {
        b2c[ct] = b2[ct * 16 + lr];
        b3c[ct] = b3[ct * 16 + lr];
        Wcc[ct] = Wc[ct * 16 + lr];
    }
    const float bcs = bcv[0];

    f32x4 acc2[8];
#pragma unroll
    for (int ct = 0; ct < 8; ++ct) acc2[ct] = (f32x4){0.f, 0.f, 0.f, 0.f};
#pragma unroll
    for (int ks = 0; ks < 4; ++ks) {
        const float* xr = xcat + lr * 132 + ks * 32 + lg * 8;
        float4 r0 = *reinterpret_cast<const float4*>(xr);
        float4 r1 = *reinterpret_cast<const float4*>(xr + 4);
        float av[8] = {r0.x, r0.y, r0.z, r0.w, r1.x, r1.y, r1.z, r1.w};
        f16x8 ah, al;
        split8(av, ah, al);
#pragma unroll
        for (int ct = 0; ct < 8; ++ct) {
            const long gg = ((long)(ks * 8 + ct) * 4 + lg) * 16 + lr;
            f16x8 bh = *reinterpret_cast<const f16x8*>(ws + 8192 + gg * 8);
            f16x8 bl = *reinterpret_cast<const f16x8*>(ws + 24576 + gg * 8);
            acc2[ct] = MFMA(al, bh, acc2[ct]);
            acc2[ct] = MFMA(ah, bl, acc2[ct]);
            acc2[ct] = MFMA(ah, bh, acc2[ct]);
        }
    }
#pragma unroll
    for (int ct = 0; ct < 8; ++ct)
#pragma unroll
        for (int j = 0; j < 4; ++j)
            xcat[(lg * 4 + j) * 132 + ct * 16 + lr] =
                lrelu(acc2[ct][j] + b2c[ct]);

#pragma unroll
    for (int ct = 0; ct < 8; ++ct) acc2[ct] = (f32x4){0.f, 0.f, 0.f, 0.f};
#pragma unroll
    for (int ks = 0; ks < 4; ++ks) {
        const float* xr = xcat + lr * 132 + ks * 32 + lg * 8;
        float4 r0 = *reinterpret_cast<const float4*>(xr);
        float4 r1 = *reinterpret_cast<const float4*>(xr + 4);
        float av[8] = {r0.x, r0.y, r0.z, r0.w, r1.x, r1.y, r1.z, r1.w};
        f16x8 ah, al;
        split8(av, ah, al);
#pragma unroll
        for (int ct = 0; ct < 8; ++ct) {
            const long gg = ((long)(ks * 8 + ct) * 4 + lg) * 16 + lr;
            f16x8 bh = *reinterpret_cast<const f16x8*>(ws + 40960 + gg * 8);
            f16x8 bl = *reinterpret_cast<const f16x8*>(ws + 57344 + gg * 8);
            acc2[ct] = MFMA(al, bh, acc2[ct]);
            acc2[ct] = MFMA(ah, bl, acc2[ct]);
            acc2[ct] = MFMA(ah, bh, acc2[ct]);
        }
    }

    // value: per-lane col partials, butterfly over the 16 cols
    float v[4];
#pragma unroll
    for (int j = 0; j < 4; ++j) {
        v[j] = lrelu(acc2[0][j] + b3c[0]) * Wcc[0];
#pragma unroll
        for (int ct = 1; ct < 8; ++ct)
            v[j] = fmaf(lrelu(acc2[ct][j] + b3c[ct]), Wcc[ct], v[j]);
        v[j] += __shfl_xor(v[j], 1, 64);
        v[j] += __shfl_xor(v[j], 2, 64);
        v[j] += __shfl_xor(v[j], 4, 64);
        v[j] += __shfl_xor(v[j], 8, 64);
    }
    if (lr == 0) {
#pragma unroll
        for (int j = 0; j < 4; ++j)
            out[ibase + lg * 4 + j] = v[j] + bcs;
    }
}

extern "C" void kernel_launch(void* const* d_in, const int* in_sizes, int n_in,
                              void* d_out, int out_size, void* d_ws, size_t ws_size,
                              hipStream_t stream) {
    (void)in_sizes; (void)n_in; (void)ws_size; (void)out_size;
    const float* obs = (const float*)d_in[0];
    const float* act = (const float*)d_in[1];
    const float* W0  = (const float*)d_in[2];
    const float* b0  = (const float*)d_in[3];
    const float* W1  = (const float*)d_in[4];
    const float* b1  = (const float*)d_in[5];
    const float* W2  = (const float*)d_in[6];
    const float* b2  = (const float*)d_in[7];
    const float* W3  = (const float*)d_in[8];
    const float* b3  = (const float*)d_in[9];
    const float* Wc  = (const float*)d_in[10];
    const float* bc  = (const float*)d_in[11];
    _Float16* ws = (_Float16*)d_ws;

    pack_weights<<<dim3(18), dim3(256), 0, stream>>>(W0, W2, W3, ws);
    critic_attention_kernel<<<dim3(65536 / 16), dim3(64), 0, stream>>>(
        obs, act, b0, W1, b1, b2, b3, Wc, bc, ws, (float*)d_out);
}